// Round 2
// baseline (138.819 us; speedup 1.0000x reference)
//
#include <hip/hip_runtime.h>
#include <hip/hip_bf16.h>
#include <stdint.h>

typedef __attribute__((ext_vector_type(8))) short short8;
typedef __attribute__((ext_vector_type(4))) float f32x4;

// ---------------- ws layout (bytes) ----------------
// Xpad granules: [b(8)][cb(8)][y(66)][x(66)][slot(4)] * 16B = 17,842,176
#define XP_BYTES   17842176
#define XP_PAD     1024
#define OFF_W9     (XP_BYTES + XP_PAD)            // 17,843,200
#define W9_BYTES   (8*9*256*32*2)                 // 1,179,648
#define OFF_BIAS   (OFF_W9 + W9_BYTES)

__device__ __forceinline__ short f2bf(float f) {
  __hip_bfloat16 h = __float2bfloat16(f);
  return *reinterpret_cast<short*>(&h);
}

__device__ __forceinline__ void gl_lds16(const void* g, void* l) {
  __builtin_amdgcn_global_load_lds(
      (const __attribute__((address_space(1))) void*)g,
      (__attribute__((address_space(3))) void*)l, 16, 0, 0);
}

// Fused weight prep: H2 slice in LDS -> Wfull rows in regs -> W9 taps + bias.
// One block per o (256 blocks), one thread per c (256 threads).
__global__ void k_weights(const float* __restrict__ core1,
                          const float* __restrict__ core2,
                          const float* __restrict__ core3,
                          const float* __restrict__ convw,
                          const float* __restrict__ convb,
                          short* __restrict__ W9, float* __restrict__ bias) {
  __shared__ float H2s[1024];   // [u(16)][j(8)][k(8)]
  __shared__ float red[256];
  const int o = blockIdx.x, c = threadIdx.x;
  const int a = o >> 6, c2 = (o >> 3) & 7, d = o & 7;
  // phase 1: H2[c2,d,u,j,k] = sum_v G2[c2,v,u,j]*G3[d,v,k]
#pragma unroll
  for (int p = 0; p < 4; ++p) {
    int idx = c + (p << 8);
    int k = idx & 7, j = (idx >> 3) & 7, u = idx >> 6;
    float s = 0.f;
#pragma unroll
    for (int v = 0; v < 16; ++v)
      s += core2[(c2 * 16 + v) * 128 + u * 8 + j] * core3[d * 128 + v * 8 + k];
    H2s[idx] = s;
  }
  __syncthreads();
  // phase 2: Wr[r] = Wfull[o,c,r] = sum_u G1[a,u,r,i]*H2s[u,j,k]
  const int i = c >> 6, j = (c >> 3) & 7, k = c & 7;
  float Wr[16];
#pragma unroll
  for (int r = 0; r < 16; ++r) Wr[r] = 0.f;
  for (int u = 0; u < 16; ++u) {
    float h = H2s[u * 64 + j * 8 + k];
    const float* c1 = core1 + (a * 16 + u) * 64 + i;
#pragma unroll
    for (int r = 0; r < 16; ++r) Wr[r] += c1[r * 4] * h;
  }
  // phase 3a: 9 conv taps, W9 layout [cb][t][o][slot][8], slot = g ^ (o&3)
  const int cb = c >> 5, cl = c & 31, g = cl >> 3, pos = cl & 7;
  const int gslot = g ^ (o & 3);
#pragma unroll
  for (int t = 0; t < 9; ++t) {
    float s = 0.f;
#pragma unroll
    for (int r = 0; r < 16; ++r) s += Wr[r] * convw[r * 9 + t];
    W9[((size_t)((cb * 9 + t) * 256 + o)) * 32 + gslot * 8 + pos] = f2bf(s);
  }
  // phase 3b: bias[o] = sum_{c,r} Wfull[o,c,r]*convb[r]
  float s = 0.f;
#pragma unroll
  for (int r = 0; r < 16; ++r) s += Wr[r] * convb[r];
  red[c] = s;
  __syncthreads();
  for (int st = 128; st > 0; st >>= 1) {
    if (c < st) red[c] += red[c + st];
    __syncthreads();
  }
  if (c == 0) bias[o] = red[0];
}

// pad+transpose: X (B,256,64,64) fp32 -> Xpad bf16 granules, INCLUDING zero
// borders (no memset needed). Grid x = padded row yp (0..65).
// slot(g, xp) = g ^ ((xp>>1)&3): bank key becomes xp&7 -> any 8 consecutive-x
// lanes in k_gemm's bfr read are conflict-free (old (xp&3) was 4-way).
__global__ void k_pad(const float* __restrict__ X, short* __restrict__ Xp) {
  const int yp = blockIdx.x, b = blockIdx.y, cb = blockIdx.z;
  const int t = threadIdx.x;
  const int x = t & 63, sub = t >> 6;       // sub = channel-group g (0..3)
  const size_t rowg = ((size_t)((b * 8 + cb) * 66 + yp)) * 264; // 66*4 granules/row
  const short8 z = (short8){0, 0, 0, 0, 0, 0, 0, 0};
  if (yp == 0 || yp == 65) {
    *(short8*)(Xp + (rowg + (size_t)(x << 2) + sub) * 8) = z;
    if (x < 2)
      *(short8*)(Xp + (rowg + (size_t)((64 + x) << 2) + sub) * 8) = z;
    return;
  }
  const int y = yp - 1, xp = x + 1;
  const int gslot = sub ^ ((xp >> 1) & 3);
  const float* src = X + ((size_t)(b * 256 + cb * 32 + sub * 8) * 64 + y) * 64 + x;
  short8 v;
#pragma unroll
  for (int k = 0; k < 8; ++k) v[k] = f2bf(src[(size_t)k * 4096]);
  *(short8*)(Xp + (rowg + (size_t)(xp << 2) + gslot) * 8) = v;
  // left/right border columns (xp = 0 and 65): zeros in all 4 slots via sub
  if (x < 2)
    *(short8*)(Xp + (rowg + (size_t)((x * 65) << 2) + sub) * 8) = z;
}

// main GEMM: out[b,o,h,w] = bias[o] + sum_{c,t} K9[o,c,t]*Xpad[b,c,h+dy,w+dx]
// Tile 8 rows x 32 o, 4 waves x (2 rows x 32 o). X-only LDS (43,008 B single
// buffer -> 2 blocks/CU = 2 waves/SIMD); W taps read direct from global
// (1KB-coalesced per (t,io), L1/L2 resident). 2 barriers per cb; the stage
// drain of one block hides under the other block's compute.
__global__ __launch_bounds__(256, 2) void k_gemm(
    const short* __restrict__ Xp, const short* __restrict__ W9,
    const float* __restrict__ bias, float* __restrict__ out) {
  __shared__ __align__(16) short XL[21504];   // 42 chunks of 1 KB = 43,008 B

  const int tid  = threadIdx.x;
  const int lane = tid & 63;
  const int wv   = tid >> 6;           // 4 waves
  const int l15  = lane & 15;
  const int gl   = lane >> 4;          // k-granule 0..3
  const int h0    = blockIdx.x << 3;   // 8 output rows / block
  const int oBase = blockIdx.y << 5;   // 32 out-channels / block
  const int b     = blockIdx.z;
  const int r0    = wv << 1;           // this wave's local output-row base

  f32x4 acc[2][2][4];
#pragma unroll
  for (int rr = 0; rr < 2; ++rr)
#pragma unroll
    for (int io = 0; io < 2; ++io)
#pragma unroll
      for (int ip = 0; ip < 4; ++ip)
        acc[rr][io][ip] = (f32x4){0.f, 0.f, 0.f, 0.f};

  for (int cb = 0; cb < 8; ++cb) {
    __syncthreads();                   // all waves done reading XL
    // stage X tile: 10 padded rows = 2640 granules = 42 KB, 42 chunks of 1 KB
    const size_t xb = ((size_t)(((b << 3) + cb) * 66 + h0) * 66) << 5;
#pragma unroll 1
    for (int q = wv; q < 42; q += 4)
      gl_lds16(Xp + xb + (q << 9) + (lane << 3), &XL[q << 9]);
    __syncthreads();                   // drain: XL ready

#pragma unroll
    for (int dx = 0; dx < 3; ++dx) {
      // W fragments for this dx straight from global (issued first: latency
      // hides under the 16 LDS reads below)
      short8 af[3][2];
#pragma unroll
      for (int dy = 0; dy < 3; ++dy)
#pragma unroll
        for (int io = 0; io < 2; ++io) {
          const int t = dy * 3 + dx;
          const int ol = (io << 4) + l15;
          af[dy][io] = *(const short8*)&W9[
              (((size_t)((cb * 9 + t) * 256 + oBase + ol)) << 5) +
              ((gl ^ (l15 & 3)) << 3)];
        }
      // X fragments for 4 consecutive padded rows (serve dy x {row0,row1})
      short8 bfr[4][4];
#pragma unroll
      for (int xr = 0; xr < 4; ++xr) {
        const int prow = r0 + xr;
#pragma unroll
        for (int ip = 0; ip < 4; ++ip) {
          const int x = (ip << 4) + l15 + dx;
          bfr[xr][ip] = *(const short8*)&XL[
              (((prow * 66 + x) << 2) + (gl ^ ((x >> 1) & 3))) << 3];
        }
      }
#pragma unroll
      for (int dy = 0; dy < 3; ++dy)
#pragma unroll
        for (int io = 0; io < 2; ++io)
#pragma unroll
          for (int ip = 0; ip < 4; ++ip) {
            acc[0][io][ip] = __builtin_amdgcn_mfma_f32_16x16x32_bf16(
                af[dy][io], bfr[dy][ip], acc[0][io][ip], 0, 0, 0);
            acc[1][io][ip] = __builtin_amdgcn_mfma_f32_16x16x32_bf16(
                af[dy][io], bfr[dy + 1][ip], acc[1][io][ip], 0, 0, 0);
          }
    }
  }

  // epilogue
#pragma unroll
  for (int rr = 0; rr < 2; ++rr) {
    const int h = h0 + r0 + rr;
#pragma unroll
    for (int io = 0; io < 2; ++io) {
#pragma unroll
      for (int r = 0; r < 4; ++r) {
        const int oG = oBase + (io << 4) + (gl << 2) + r;
        const float bv = bias[oG];
        float* op = out + (((size_t)((b << 8) + oG)) << 12) + (h << 6);
#pragma unroll
        for (int ip = 0; ip < 4; ++ip)
          op[(ip << 4) + l15] = acc[rr][io][ip][r] + bv;
      }
    }
  }
}

extern "C" void kernel_launch(void* const* d_in, const int* in_sizes, int n_in,
                              void* d_out, int out_size, void* d_ws, size_t ws_size,
                              hipStream_t stream) {
  (void)in_sizes; (void)n_in; (void)out_size; (void)ws_size;
  const float* X     = (const float*)d_in[0];
  const float* convw = (const float*)d_in[1];
  const float* convb = (const float*)d_in[2];
  const float* core1 = (const float*)d_in[3];
  const float* core2 = (const float*)d_in[4];
  const float* core3 = (const float*)d_in[5];
  float* out = (float*)d_out;
  char*  ws  = (char*)d_ws;

  short* Xp   = (short*)ws;
  short* W9   = (short*)(ws + OFF_W9);
  float* bias = (float*)(ws + OFF_BIAS);

  // no memset: k_pad writes every Xpad granule (borders = zero granules)
  k_weights<<<256, 256, 0, stream>>>(core1, core2, core3, convw, convb, W9, bias);
  k_pad    <<<dim3(66, 8, 8), 256, 0, stream>>>(X, Xp);
  k_gemm   <<<dim3(8, 8, 8), 256, 0, stream>>>(Xp, W9, bias, out);
}

// Round 3
// 137.194 us; speedup vs baseline: 1.0118x; 1.0118x over previous
//
#include <hip/hip_runtime.h>
#include <hip/hip_bf16.h>
#include <stdint.h>

typedef __attribute__((ext_vector_type(8))) short short8;
typedef __attribute__((ext_vector_type(4))) float f32x4;

// ---------------- ws layout (bytes) ----------------
// Xpad granules: [b(8)][cb(8)][y(66)][x(66)][slot(4)] * 16B = 17,842,176
#define XP_BYTES   17842176
#define XP_PAD     1024
#define OFF_W9     (XP_BYTES + XP_PAD)            // 17,843,200
#define W9_BYTES   (8*9*256*32*2)                 // 1,179,648
#define OFF_BIAS   (OFF_W9 + W9_BYTES)

__device__ __forceinline__ short f2bf(float f) {
  __hip_bfloat16 h = __float2bfloat16(f);
  return *reinterpret_cast<short*>(&h);
}

__device__ __forceinline__ void gl_lds16(const void* g, void* l) {
  __builtin_amdgcn_global_load_lds(
      (const __attribute__((address_space(1))) void*)g,
      (__attribute__((address_space(3))) void*)l, 16, 0, 0);
}

// Fused weight prep: H2 slice in LDS -> Wfull rows in regs -> W9 taps + bias.
// One block per o (256 blocks), one thread per c (256 threads).
__global__ void k_weights(const float* __restrict__ core1,
                          const float* __restrict__ core2,
                          const float* __restrict__ core3,
                          const float* __restrict__ convw,
                          const float* __restrict__ convb,
                          short* __restrict__ W9, float* __restrict__ bias) {
  __shared__ float H2s[1024];   // [u(16)][j(8)][k(8)]
  __shared__ float red[256];
  const int o = blockIdx.x, c = threadIdx.x;
  const int a = o >> 6, c2 = (o >> 3) & 7, d = o & 7;
  // phase 1: H2[c2,d,u,j,k] = sum_v G2[c2,v,u,j]*G3[d,v,k]
#pragma unroll
  for (int p = 0; p < 4; ++p) {
    int idx = c + (p << 8);
    int k = idx & 7, j = (idx >> 3) & 7, u = idx >> 6;
    float s = 0.f;
#pragma unroll
    for (int v = 0; v < 16; ++v)
      s += core2[(c2 * 16 + v) * 128 + u * 8 + j] * core3[d * 128 + v * 8 + k];
    H2s[idx] = s;
  }
  __syncthreads();
  // phase 2: Wr[r] = Wfull[o,c,r] = sum_u G1[a,u,r,i]*H2s[u,j,k]
  const int i = c >> 6, j = (c >> 3) & 7, k = c & 7;
  float Wr[16];
#pragma unroll
  for (int r = 0; r < 16; ++r) Wr[r] = 0.f;
  for (int u = 0; u < 16; ++u) {
    float h = H2s[u * 64 + j * 8 + k];
    const float* c1 = core1 + (a * 16 + u) * 64 + i;
#pragma unroll
    for (int r = 0; r < 16; ++r) Wr[r] += c1[r * 4] * h;
  }
  // phase 3a: 9 conv taps, W9 layout [cb][t][o][slot][8], slot = g ^ (o&3)
  const int cb = c >> 5, cl = c & 31, g = cl >> 3, pos = cl & 7;
  const int gslot = g ^ (o & 3);
#pragma unroll
  for (int t = 0; t < 9; ++t) {
    float s = 0.f;
#pragma unroll
    for (int r = 0; r < 16; ++r) s += Wr[r] * convw[r * 9 + t];
    W9[((size_t)((cb * 9 + t) * 256 + o)) * 32 + gslot * 8 + pos] = f2bf(s);
  }
  // phase 3b: bias[o] = sum_{c,r} Wfull[o,c,r]*convb[r]
  float s = 0.f;
#pragma unroll
  for (int r = 0; r < 16; ++r) s += Wr[r] * convb[r];
  red[c] = s;
  __syncthreads();
  for (int st = 128; st > 0; st >>= 1) {
    if (c < st) red[c] += red[c + st];
    __syncthreads();
  }
  if (c == 0) bias[o] = red[0];
}

// pad+transpose: X (B,256,64,64) fp32 -> Xpad bf16 granules, INCLUDING zero
// borders (no memset needed). Grid x = padded row yp (0..65).
// slot(g, xp) = g ^ ((xp>>1)&3): bank key becomes xp&7 -> any 8 consecutive-x
// lanes in k_gemm's bfr read are conflict-free.
__global__ void k_pad(const float* __restrict__ X, short* __restrict__ Xp) {
  const int yp = blockIdx.x, b = blockIdx.y, cb = blockIdx.z;
  const int t = threadIdx.x;
  const int x = t & 63, sub = t >> 6;       // sub = channel-group g (0..3)
  const size_t rowg = ((size_t)((b * 8 + cb) * 66 + yp)) * 264; // 66*4 granules/row
  const short8 z = (short8){0, 0, 0, 0, 0, 0, 0, 0};
  if (yp == 0 || yp == 65) {
    *(short8*)(Xp + (rowg + (size_t)(x << 2) + sub) * 8) = z;
    if (x < 2)
      *(short8*)(Xp + (rowg + (size_t)((64 + x) << 2) + sub) * 8) = z;
    return;
  }
  const int y = yp - 1, xp = x + 1;
  const int gslot = sub ^ ((xp >> 1) & 3);
  const float* src = X + ((size_t)(b * 256 + cb * 32 + sub * 8) * 64 + y) * 64 + x;
  short8 v;
#pragma unroll
  for (int k = 0; k < 8; ++k) v[k] = f2bf(src[(size_t)k * 4096]);
  *(short8*)(Xp + (rowg + (size_t)(xp << 2) + gslot) * 8) = v;
  // left/right border columns (xp = 0 and 65): zeros in all 4 slots via sub
  if (x < 2)
    *(short8*)(Xp + (rowg + (size_t)((x * 65) << 2) + sub) * 8) = z;
}

// main GEMM: out[b,o,h,w] = bias[o] + sum_{c,t} K9[o,c,t]*Xpad[b,c,h+dy,w+dx]
// Block = 16 rows x 32 o, 512 threads (8 waves), wave = 2 rows x 32 o.
// Grid (4,8,8) = 256 blocks = 1/CU -> 2 waves/SIMD. X-only LDS double buffer
// (2 x 76.8 KB). Pipeline: ONE barrier per cb; stage(cb+1) issued right after
// it, lands during compute(cb), drained for free at the next barrier.
// Compute phase has NO VGPR-dest VMEM loads (af preloaded before the stage
// issue), so no compiler vmcnt wait can drain the in-flight prefetch.
__global__ __launch_bounds__(512, 1) void k_gemm(
    const short* __restrict__ Xp, const short* __restrict__ W9,
    const float* __restrict__ bias, float* __restrict__ out) {
  __shared__ __align__(16) short XL[2][38400];  // 2 x 75 KB-chunks = 153,600 B

  const int tid  = threadIdx.x;
  const int lane = tid & 63;
  const int wv   = tid >> 6;           // 8 waves
  const int l15  = lane & 15;
  const int gl   = lane >> 4;          // k-granule 0..3
  const int h0    = blockIdx.x << 4;   // 16 output rows / block
  const int oBase = blockIdx.y << 5;   // 32 out-channels / block
  const int b     = blockIdx.z;
  const int r0    = wv << 1;           // wave's local output-row base (0..14)

  f32x4 acc[2][2][4];
#pragma unroll
  for (int rr = 0; rr < 2; ++rr)
#pragma unroll
    for (int io = 0; io < 2; ++io)
#pragma unroll
      for (int ip = 0; ip < 4; ++ip)
        acc[rr][io][ip] = (f32x4){0.f, 0.f, 0.f, 0.f};

  // tile = 18 padded rows x 66 x 4 granules = 76,032 B -> 75 chunks of 1 KB
  // (chunk 74 over-reads 768 B into the next region / XP_PAD: harmless)
  const size_t xrow = ((size_t)(b << 3) * 66 + h0) * 66;  // row-linear base/66
  // prologue: stage cb=0 into buffer 0
  {
    const size_t xb = (((size_t)((b << 3) + 0) * 66 + h0) * 66) << 5;
#pragma unroll 1
    for (int q = wv; q < 75; q += 8)
      gl_lds16(Xp + xb + (q << 9) + (lane << 3), &XL[0][q << 9]);
  }

  for (int cb = 0; cb < 8; ++cb) {
    // af preload for ALL 9 taps of this cb (global, L2-hot, 18 x b128).
    // Issued BEFORE the stage so compiler waits for af never drain the stage.
    short8 af[9][2];
#pragma unroll
    for (int t = 0; t < 9; ++t)
#pragma unroll
      for (int io = 0; io < 2; ++io) {
        const int ol = (io << 4) + l15;
        af[t][io] = *(const short8*)&W9[
            (((size_t)((cb * 9 + t) * 256 + oBase + ol)) << 5) +
            ((gl ^ (l15 & 3)) << 3)];
      }
    __builtin_amdgcn_sched_barrier(0);

    __syncthreads();   // drains stage(cb) (landed during compute(cb-1)) [+af]

    if (cb < 7) {      // issue stage(cb+1) into the other buffer
      const size_t xb = (((size_t)((b << 3) + cb + 1) * 66 + h0) * 66) << 5;
      short* dst = &XL[(cb + 1) & 1][0];
#pragma unroll 1
      for (int q = wv; q < 75; q += 8)
        gl_lds16(Xp + xb + (q << 9) + (lane << 3), dst + (q << 9));
    }
    __builtin_amdgcn_sched_barrier(0);

    const short* XLc = &XL[cb & 1][0];
#pragma unroll
    for (int dx = 0; dx < 3; ++dx) {
      // X fragments for 4 consecutive padded rows (serve dy x {row0,row1})
      short8 bfr[4][4];
#pragma unroll
      for (int xr = 0; xr < 4; ++xr) {
        const int prow = r0 + xr;
#pragma unroll
        for (int ip = 0; ip < 4; ++ip) {
          const int x = (ip << 4) + l15 + dx;
          bfr[xr][ip] = *(const short8*)&XLc[
              (((prow * 66 + x) << 2) + (gl ^ ((x >> 1) & 3))) << 3];
        }
      }
#pragma unroll
      for (int dy = 0; dy < 3; ++dy) {
        const int t = dy * 3 + dx;
#pragma unroll
        for (int io = 0; io < 2; ++io)
#pragma unroll
          for (int ip = 0; ip < 4; ++ip) {
            acc[0][io][ip] = __builtin_amdgcn_mfma_f32_16x16x32_bf16(
                af[t][io], bfr[dy][ip], acc[0][io][ip], 0, 0, 0);
            acc[1][io][ip] = __builtin_amdgcn_mfma_f32_16x16x32_bf16(
                af[t][io], bfr[dy + 1][ip], acc[1][io][ip], 0, 0, 0);
          }
      }
    }
  }
  (void)xrow;

  // epilogue
#pragma unroll
  for (int rr = 0; rr < 2; ++rr) {
    const int h = h0 + r0 + rr;
#pragma unroll
    for (int io = 0; io < 2; ++io) {
#pragma unroll
      for (int r = 0; r < 4; ++r) {
        const int oG = oBase + (io << 4) + (gl << 2) + r;
        const float bv = bias[oG];
        float* op = out + (((size_t)((b << 8) + oG)) << 12) + (h << 6);
#pragma unroll
        for (int ip = 0; ip < 4; ++ip)
          op[(ip << 4) + l15] = acc[rr][io][ip][r] + bv;
      }
    }
  }
}

extern "C" void kernel_launch(void* const* d_in, const int* in_sizes, int n_in,
                              void* d_out, int out_size, void* d_ws, size_t ws_size,
                              hipStream_t stream) {
  (void)in_sizes; (void)n_in; (void)out_size; (void)ws_size;
  const float* X     = (const float*)d_in[0];
  const float* convw = (const float*)d_in[1];
  const float* convb = (const float*)d_in[2];
  const float* core1 = (const float*)d_in[3];
  const float* core2 = (const float*)d_in[4];
  const float* core3 = (const float*)d_in[5];
  float* out = (float*)d_out;
  char*  ws  = (char*)d_ws;

  short* Xp   = (short*)ws;
  short* W9   = (short*)(ws + OFF_W9);
  float* bias = (float*)(ws + OFF_BIAS);

  // no memset: k_pad writes every Xpad granule (borders = zero granules)
  k_weights<<<256, 256, 0, stream>>>(core1, core2, core3, convw, convb, W9, bias);
  k_pad    <<<dim3(66, 8, 8), 256, 0, stream>>>(X, Xp);
  k_gemm   <<<dim3(4, 8, 8), 512, 0, stream>>>(Xp, W9, bias, out);
}

// Round 4
// 135.382 us; speedup vs baseline: 1.0254x; 1.0134x over previous
//
#include <hip/hip_runtime.h>
#include <hip/hip_bf16.h>
#include <stdint.h>

typedef __attribute__((ext_vector_type(8))) short short8;
typedef __attribute__((ext_vector_type(4))) float f32x4;

// ---------------- ws layout (bytes) ----------------
// Xpad granules: [b(8)][cb(8)][y(66)][x(66)][slot(4)] * 16B = 17,842,176
#define XP_BYTES   17842176
#define XP_PAD     1024
#define OFF_W9     (XP_BYTES + XP_PAD)            // 17,843,200
#define W9_BYTES   (8*9*256*32*2)                 // 1,179,648
#define OFF_BIAS   (OFF_W9 + W9_BYTES)

__device__ __forceinline__ short f2bf(float f) {
  __hip_bfloat16 h = __float2bfloat16(f);
  return *reinterpret_cast<short*>(&h);
}

__device__ __forceinline__ void gl_lds16(const void* g, void* l) {
  __builtin_amdgcn_global_load_lds(
      (const __attribute__((address_space(1))) void*)g,
      (__attribute__((address_space(3))) void*)l, 16, 0, 0);
}

// Fused weight prep: H2 slice in LDS -> Wfull rows in regs -> W9 taps + bias.
// One block per o (256 blocks), one thread per c (256 threads).
__global__ void k_weights(const float* __restrict__ core1,
                          const float* __restrict__ core2,
                          const float* __restrict__ core3,
                          const float* __restrict__ convw,
                          const float* __restrict__ convb,
                          short* __restrict__ W9, float* __restrict__ bias) {
  __shared__ float H2s[1024];   // [u(16)][j(8)][k(8)]
  __shared__ float red[256];
  const int o = blockIdx.x, c = threadIdx.x;
  const int a = o >> 6, c2 = (o >> 3) & 7, d = o & 7;
  // phase 1: H2[c2,d,u,j,k] = sum_v G2[c2,v,u,j]*G3[d,v,k]
#pragma unroll
  for (int p = 0; p < 4; ++p) {
    int idx = c + (p << 8);
    int k = idx & 7, j = (idx >> 3) & 7, u = idx >> 6;
    float s = 0.f;
#pragma unroll
    for (int v = 0; v < 16; ++v)
      s += core2[(c2 * 16 + v) * 128 + u * 8 + j] * core3[d * 128 + v * 8 + k];
    H2s[idx] = s;
  }
  __syncthreads();
  // phase 2: Wr[r] = Wfull[o,c,r] = sum_u G1[a,u,r,i]*H2s[u,j,k]
  const int i = c >> 6, j = (c >> 3) & 7, k = c & 7;
  float Wr[16];
#pragma unroll
  for (int r = 0; r < 16; ++r) Wr[r] = 0.f;
  for (int u = 0; u < 16; ++u) {
    float h = H2s[u * 64 + j * 8 + k];
    const float* c1 = core1 + (a * 16 + u) * 64 + i;
#pragma unroll
    for (int r = 0; r < 16; ++r) Wr[r] += c1[r * 4] * h;
  }
  // phase 3a: 9 conv taps, W9 layout [cb][t][o][slot][8], slot = g ^ (o&3)
  const int cb = c >> 5, cl = c & 31, g = cl >> 3, pos = cl & 7;
  const int gslot = g ^ (o & 3);
#pragma unroll
  for (int t = 0; t < 9; ++t) {
    float s = 0.f;
#pragma unroll
    for (int r = 0; r < 16; ++r) s += Wr[r] * convw[r * 9 + t];
    W9[((size_t)((cb * 9 + t) * 256 + o)) * 32 + gslot * 8 + pos] = f2bf(s);
  }
  // phase 3b: bias[o] = sum_{c,r} Wfull[o,c,r]*convb[r]
  float s = 0.f;
#pragma unroll
  for (int r = 0; r < 16; ++r) s += Wr[r] * convb[r];
  red[c] = s;
  __syncthreads();
  for (int st = 128; st > 0; st >>= 1) {
    if (c < st) red[c] += red[c + st];
    __syncthreads();
  }
  if (c == 0) bias[o] = red[0];
}

// pad+transpose: X (B,256,64,64) fp32 -> Xpad bf16 granules, INCLUDING zero
// borders (no memset needed). Grid x = padded row yp (0..65).
// slot(g, xp) = g ^ ((xp>>1)&3): bank key becomes xp&7 -> any 8 consecutive-x
// lanes in k_gemm's bfr read are conflict-free.
__global__ void k_pad(const float* __restrict__ X, short* __restrict__ Xp) {
  const int yp = blockIdx.x, b = blockIdx.y, cb = blockIdx.z;
  const int t = threadIdx.x;
  const int x = t & 63, sub = t >> 6;       // sub = channel-group g (0..3)
  const size_t rowg = ((size_t)((b * 8 + cb) * 66 + yp)) * 264; // 66*4 granules/row
  const short8 z = (short8){0, 0, 0, 0, 0, 0, 0, 0};
  if (yp == 0 || yp == 65) {
    *(short8*)(Xp + (rowg + (size_t)(x << 2) + sub) * 8) = z;
    if (x < 2)
      *(short8*)(Xp + (rowg + (size_t)((64 + x) << 2) + sub) * 8) = z;
    return;
  }
  const int y = yp - 1, xp = x + 1;
  const int gslot = sub ^ ((xp >> 1) & 3);
  const float* src = X + ((size_t)(b * 256 + cb * 32 + sub * 8) * 64 + y) * 64 + x;
  short8 v;
#pragma unroll
  for (int k = 0; k < 8; ++k) v[k] = f2bf(src[(size_t)k * 4096]);
  *(short8*)(Xp + (rowg + (size_t)(xp << 2) + gslot) * 8) = v;
  // left/right border columns (xp = 0 and 65): zeros in all 4 slots via sub
  if (x < 2)
    *(short8*)(Xp + (rowg + (size_t)((x * 65) << 2) + sub) * 8) = z;
}

// main GEMM: out[b,o,h,w] = bias[o] + sum_{c,t} K9[o,c,t]*Xpad[b,c,h+dy,w+dx]
// Block = 16 rows x 32 o, 512 threads (8 waves), wave = 2 rows x 32 o.
// Grid (4,8,8) = 256 blocks = 1/CU -> 2 waves/SIMD. X-only LDS double buffer.
// One barrier per cb; stage(cb+1) issued after it, drained at next barrier.
// Inner loop: 12 steps (3 dx x 4 ip), register-double-buffered bfr prefetch
// (4 ds_read_b128 / step, fully static unroll) overlapped with a 12-MFMA
// cluster wrapped in setprio (T5). ds_read addresses precomputed so step
// offsets fold to immediates.
__global__ __launch_bounds__(512, 1) void k_gemm(
    const short* __restrict__ Xp, const short* __restrict__ W9,
    const float* __restrict__ bias, float* __restrict__ out) {
  __shared__ __align__(16) short XL[2][38400];  // 2 x 76.8 KB = 153.6 KB

  const int tid  = threadIdx.x;
  const int lane = tid & 63;
  const int wv   = tid >> 6;           // 8 waves
  const int l15  = lane & 15;
  const int gl   = lane >> 4;          // k-granule 0..3
  const int h0    = blockIdx.x << 4;   // 16 output rows / block
  const int oBase = blockIdx.y << 5;   // 32 out-channels / block
  const int b     = blockIdx.z;
  const int r0    = wv << 1;           // wave's local output-row base (0..14)

  // precomputed LDS short-offsets: xoff[xr][dx] for row r0+xr, x=l15+dx (+16ip)
  int xoff[4][3];
#pragma unroll
  for (int xr = 0; xr < 4; ++xr)
#pragma unroll
    for (int dx = 0; dx < 3; ++dx)
      xoff[xr][dx] = ((r0 + xr) * 66 + l15 + dx) * 32 +
                     ((gl ^ (((l15 + dx) >> 1) & 3)) << 3);

  // af lane offset (shorts) into W9: per (cb,t,io) add cb*73728+t*8192+io*512
  const int laneW = (oBase + l15) * 32 + ((gl ^ (l15 & 3)) << 3);

  f32x4 acc[2][2][4];
#pragma unroll
  for (int rr = 0; rr < 2; ++rr)
#pragma unroll
    for (int io = 0; io < 2; ++io)
#pragma unroll
      for (int ip = 0; ip < 4; ++ip)
        acc[rr][io][ip] = (f32x4){0.f, 0.f, 0.f, 0.f};

  // stage helper: 18 padded rows x 264 granules = 76,032 B -> 75 x 1KB chunks
  // (chunk 74 over-reads 768 B of the next slab: in-bounds, unused)
#define STAGE(CB, BUF)                                                     \
  {                                                                        \
    const size_t xb = ((size_t)(((b << 3) + (CB)) * 66 + h0) * 66) << 5;   \
    _Pragma("unroll 1")                                                    \
    for (int q = wv; q < 75; q += 8)                                       \
      gl_lds16(Xp + xb + (q << 9) + (lane << 3), &XL[BUF][q << 9]);        \
  }

  STAGE(0, 0);   // prologue

  for (int cb = 0; cb < 8; ++cb) {
    // af preload: 18 global b128, issued BEFORE the barrier so the barrier's
    // drain covers them (no vmcnt wait can ever drain the next stage queue)
    const short* Wc = W9 + cb * 73728 + laneW;
    short8 af[9][2];
#pragma unroll
    for (int t = 0; t < 9; ++t)
#pragma unroll
      for (int io = 0; io < 2; ++io)
        af[t][io] = *(const short8*)&Wc[t * 8192 + (io << 9)];
    __builtin_amdgcn_sched_barrier(0);

    __syncthreads();   // drains stage(cb) (+af); XL[cb&1] ready

    if (cb < 7) STAGE(cb + 1, (cb + 1) & 1);
    __builtin_amdgcn_sched_barrier(0);

    const short* XLc = &XL[cb & 1][0];
    short8 bfr[2][4];  // [regbuf][xr], static-indexed (full unroll)

#define LOADS(BUF, DX, IP)                                                 \
  {                                                                        \
    _Pragma("unroll")                                                      \
    for (int xr = 0; xr < 4; ++xr)                                         \
      bfr[BUF][xr] = *(const short8*)&XLc[xoff[xr][DX] + ((IP) << 9)];     \
  }

    LOADS(0, 0, 0);    // step-0 fragments
#pragma unroll
    for (int s = 0; s < 12; ++s) {
      const int dx = s >> 2, ip = s & 3, buf = s & 1;
      if (s < 11) LOADS(buf ^ 1, (s + 1) >> 2, (s + 1) & 3);
      __builtin_amdgcn_sched_barrier(0);   // reads issued before MFMA cluster
      __builtin_amdgcn_s_setprio(1);
#pragma unroll
      for (int dy = 0; dy < 3; ++dy) {
        const int t = dy * 3 + dx;
#pragma unroll
        for (int io = 0; io < 2; ++io) {
          acc[0][io][ip] = __builtin_amdgcn_mfma_f32_16x16x32_bf16(
              af[t][io], bfr[buf][dy], acc[0][io][ip], 0, 0, 0);
          acc[1][io][ip] = __builtin_amdgcn_mfma_f32_16x16x32_bf16(
              af[t][io], bfr[buf][dy + 1], acc[1][io][ip], 0, 0, 0);
        }
      }
      __builtin_amdgcn_s_setprio(0);
    }
#undef LOADS
  }
#undef STAGE

  // epilogue
#pragma unroll
  for (int rr = 0; rr < 2; ++rr) {
    const int h = h0 + r0 + rr;
#pragma unroll
    for (int io = 0; io < 2; ++io) {
#pragma unroll
      for (int r = 0; r < 4; ++r) {
        const int oG = oBase + (io << 4) + (gl << 2) + r;
        const float bv = bias[oG];
        float* op = out + (((size_t)((b << 8) + oG)) << 12) + (h << 6);
#pragma unroll
        for (int ip = 0; ip < 4; ++ip)
          op[(ip << 4) + l15] = acc[rr][io][ip][r] + bv;
      }
    }
  }
}

extern "C" void kernel_launch(void* const* d_in, const int* in_sizes, int n_in,
                              void* d_out, int out_size, void* d_ws, size_t ws_size,
                              hipStream_t stream) {
  (void)in_sizes; (void)n_in; (void)out_size; (void)ws_size;
  const float* X     = (const float*)d_in[0];
  const float* convw = (const float*)d_in[1];
  const float* convb = (const float*)d_in[2];
  const float* core1 = (const float*)d_in[3];
  const float* core2 = (const float*)d_in[4];
  const float* core3 = (const float*)d_in[5];
  float* out = (float*)d_out;
  char*  ws  = (char*)d_ws;

  short* Xp   = (short*)ws;
  short* W9   = (short*)(ws + OFF_W9);
  float* bias = (float*)(ws + OFF_BIAS);

  // no memset: k_pad writes every Xpad granule (borders = zero granules)
  k_weights<<<256, 256, 0, stream>>>(core1, core2, core3, convw, convb, W9, bias);
  k_pad    <<<dim3(66, 8, 8), 256, 0, stream>>>(X, Xp);
  k_gemm   <<<dim3(4, 8, 8), 512, 0, stream>>>(Xp, W9, bias, out);
}